// Round 7
// baseline (160.145 us; speedup 1.0000x reference)
//
#include <hip/hip_runtime.h>
#include <hip/hip_bf16.h>
#include <math.h>

typedef __bf16 bf16;
typedef __bf16 bf16x8 __attribute__((ext_vector_type(8)));
typedef __bf16 bf16x4 __attribute__((ext_vector_type(4)));
typedef float f32x4 __attribute__((ext_vector_type(4)));
typedef float f32x16 __attribute__((ext_vector_type(16)));

#define DEV __device__ __forceinline__
#define AS1(p) ((const __attribute__((address_space(1))) void*)(p))
#define AS3(p) ((__attribute__((address_space(3))) void*)(p))

// ---------------- problem sizes ----------------
#define Bsz 2
#define Lseq 2048
#define Dm 1024
#define Hh 16
#define HD 64
#define BL (Bsz * Lseq)   // 4096 rows
#define TN (3 * Dm)       // 3072

#define LOG2E 1.44269504088896f

// ---------------- workspace layout (bytes) ----------------
#define OFF_XATT  ((size_t)0)                            // xbf bf16 8.39MB; att aliases after gemm1
#define OFF_WQKVT (OFF_XATT  + (size_t)BL * Dm * 2)      // 6.29MB
#define OFF_WOUTT (OFF_WQKVT + (size_t)TN * Dm * 2)      // 2.10MB
#define OFF_TAB   (OFF_WOUTT + (size_t)Dm * Dm * 2)      // 0.52MB
#define OFF_Q     (OFF_TAB   + (size_t)Lseq * 32 * 8)    // 8.39MB q bf16 [32][2048][64]
#define OFF_K     (OFF_Q     + (size_t)BL * Dm * 2)      // 8.39MB
#define OFF_VT    (OFF_K     + (size_t)BL * Dm * 2)      // 8.39MB vT bf16 [32][64][2048]
// end = 42.5 MB

DEV float exp2_fast(float x) {   // 2^x, single v_exp_f32
    float r;
    asm("v_exp_f32 %0, %1" : "=v"(r) : "v"(x));
    return r;
}

// ---------------- stage 0: convert x to bf16 ----------------
__global__ __launch_bounds__(256) void k_convert(const float* __restrict__ in,
                                                 bf16* __restrict__ out) {
    int i = blockIdx.x * 256 + threadIdx.x;
    const float4* in4 = (const float4*)in;
    float4 a = in4[i * 2];
    float4 b = in4[i * 2 + 1];
    bf16x8 o;
    o[0] = (bf16)a.x; o[1] = (bf16)a.y; o[2] = (bf16)a.z; o[3] = (bf16)a.w;
    o[4] = (bf16)b.x; o[5] = (bf16)b.y; o[6] = (bf16)b.z; o[7] = (bf16)b.w;
    ((bf16x8*)out)[i] = o;
}

// ---------------- stage 0b: transpose fp32 [R][C] -> bf16 [C][R] ----------------
__global__ __launch_bounds__(256) void k_transpose(const float* __restrict__ in,
                                                   bf16* __restrict__ out,
                                                   int R, int C) {
    __shared__ float t[32][33];
    int bx = blockIdx.x * 32;
    int by = blockIdx.y * 32;
    int tx = threadIdx.x, ty = threadIdx.y;
#pragma unroll
    for (int i = 0; i < 32; i += 8)
        t[ty + i][tx] = in[(size_t)(by + ty + i) * C + bx + tx];
    __syncthreads();
#pragma unroll
    for (int i = 0; i < 32; i += 8)
        out[(size_t)(bx + ty + i) * R + by + tx] = (bf16)t[tx][ty + i];
}

// ---------------- stage 0c: sin/cos table [2048][32] {sin,cos} ----------------
__global__ __launch_bounds__(256) void k_sincos(float2* __restrict__ tab) {
    int idx = blockIdx.x * 256 + threadIdx.x;
    int pos = idx >> 5, t = idx & 31;
    float theta = powf(10000.0f, -(float)t * (1.0f / 32.0f));
    float f = (float)pos * theta;
    tab[idx] = make_float2(sinf(f), cosf(f));
}

// ---------------- bf16 GEMM, 128x128 tile, BK=64 ----------------
// global_load_lds staging: LINEAR LDS dest, XOR swizzle pre-applied to the
// global SOURCE chunk (rule #21); ds_reads apply the same XOR.
// Epilogue loops fully unrolled (rule #20).
template <int EPI>
DEV void gemm_body(const bf16* __restrict__ A,
                   const bf16* __restrict__ BT,
                   const float* __restrict__ bias,
                   float* __restrict__ C,
                   bf16* __restrict__ qo,
                   bf16* __restrict__ ko,
                   bf16* __restrict__ vt,
                   const float2* __restrict__ tab,
                   int N, int K) {
    __shared__ uint4 smem4[2048];   // 32KB: A tile 16KB + B tile 16KB
    char* Al = (char*)smem4;
    char* Bl = (char*)smem4 + 16384;
    const int tid = threadIdx.x;
    const int w = tid >> 6, lane = tid & 63, lg = lane >> 4, lr = lane & 15;
    const int m0 = blockIdx.y * 128, n0 = blockIdx.x * 128;
    const int wm = (w >> 1) * 64, wn = (w & 1) * 64;
    const char* Ab = (const char*)A;
    const char* Bb = (const char*)BT;
    const size_t Kb = (size_t)K * 2;

    f32x4 acc[4][4] = {};

    const int rowL = lane >> 3;                    // 0..7 within 8-row group
    const int j16 = ((lane & 7) ^ rowL) * 16;      // pre-swizzled source chunk byte

    for (int kt = 0; kt < K; kt += 64) {
#pragma unroll
        for (int c = 0; c < 4; ++c) {
            const int R0 = (w * 4 + c) * 8;
            const int row = R0 + rowL;
            __builtin_amdgcn_global_load_lds(AS1(Ab + (size_t)(m0 + row) * Kb + kt * 2 + j16),
                                             AS3(Al + R0 * 128), 16, 0, 0);
            __builtin_amdgcn_global_load_lds(AS1(Bb + (size_t)(n0 + row) * Kb + kt * 2 + j16),
                                             AS3(Bl + R0 * 128), 16, 0, 0);
        }
        __syncthreads();
#pragma unroll
        for (int kf = 0; kf < 2; ++kf) {
            bf16x8 af[4], bfr[4];
#pragma unroll
            for (int i = 0; i < 4; ++i) {
                int ra = wm + i * 16 + lr;
                af[i] = *(const bf16x8*)(Al + ra * 128 + ((kf * 64 + lg * 16) ^ ((ra & 7) << 4)));
                int rb = wn + i * 16 + lr;
                bfr[i] = *(const bf16x8*)(Bl + rb * 128 + ((kf * 64 + lg * 16) ^ ((rb & 7) << 4)));
            }
#pragma unroll
            for (int i = 0; i < 4; ++i)
#pragma unroll
                for (int j = 0; j < 4; ++j)
                    acc[i][j] = __builtin_amdgcn_mfma_f32_16x16x32_bf16(af[i], bfr[j], acc[i][j], 0, 0, 0);
        }
        __syncthreads();
    }

    if constexpr (EPI == 0) {
#pragma unroll
        for (int i = 0; i < 4; ++i) {
            int row = m0 + wm + i * 16 + lg * 4;
#pragma unroll
            for (int j = 0; j < 4; ++j) {
                int col = n0 + wn + j * 16 + lr;
                float bv = bias[col];
#pragma unroll
                for (int r = 0; r < 4; ++r)
                    C[(size_t)(row + r) * N + col] = acc[i][j][r] + bv;
            }
        }
    } else {
        const int phase = n0 >> 10;            // 0=q 1=k 2=v
        const int c0 = n0 + wn;
        const int h = (c0 & 1023) >> 6;
        const int b = m0 >> 11;
        const int bh = b * 16 + h;
        const int lbase = (m0 & 2047) + wm;
        float bv[4];
#pragma unroll
        for (int j = 0; j < 4; ++j) bv[j] = bias[c0 + j * 16 + lr];
        float* Lw = (float*)((char*)smem4 + w * 4096);

#pragma unroll   // FULL unroll: compile-time acc indices (rule #20)
        for (int i = 0; i < 4; ++i) {
#pragma unroll
            for (int j = 0; j < 4; ++j)
#pragma unroll
                for (int r = 0; r < 4; ++r)
                    Lw[(lg * 4 + r) * 64 + j * 16 + lr] = acc[i][j][r] + bv[j];
            __syncthreads();
            if (phase < 2) {
                // q gets 1/8 (scores) * log2e (exp2-domain softmax) folded in
                const float scale = (phase == 0) ? 0.125f * LOG2E : 1.0f;
                bf16* dst = (phase == 0 ? qo : ko) + (size_t)bh * Lseq * 64;
#pragma unroll
                for (int j = 0; j < 4; ++j)
#pragma unroll
                    for (int r = 0; r < 4; ++r) {
                        int rl = lg * 4 + r;
                        int d = j * 16 + lr;
                        int l = lbase + i * 16 + rl;
                        float v = Lw[rl * 64 + d];
                        int dp = (d < 32) ? (2 * d + 1) : (2 * d - 64);
                        float p = Lw[rl * 64 + dp];
                        float2 f = tab[l * 32 + (d & 31)];
                        float val = ((d < 32) ? (v - p) * f.x : (v + p) * f.y) * scale;
                        dst[(size_t)l * 64 + d] = (bf16)val;
                    }
            } else {
                int d = lane;
                int lb = lbase + i * 16;
                bf16x8 o1, o2;
#pragma unroll
                for (int rw = 0; rw < 8; ++rw) {
                    o1[rw] = (bf16)Lw[rw * 64 + d];
                    o2[rw] = (bf16)Lw[(rw + 8) * 64 + d];
                }
                bf16* dst = vt + ((size_t)bh * 64 + d) * Lseq + lb;
                *(bf16x8*)dst = o1;
                *(bf16x8*)(dst + 8) = o2;
            }
            __syncthreads();
        }
    }
}

__global__ __launch_bounds__(256) void k_gemm_qkv(const bf16* __restrict__ A,
                                                  const bf16* __restrict__ BT,
                                                  const float* __restrict__ bias,
                                                  bf16* __restrict__ qo,
                                                  bf16* __restrict__ ko,
                                                  bf16* __restrict__ vt,
                                                  const float2* __restrict__ tab) {
    gemm_body<1>(A, BT, bias, nullptr, qo, ko, vt, tab, TN, Dm);
}
__global__ __launch_bounds__(256) void k_gemm_out(const bf16* __restrict__ A,
                                                  const bf16* __restrict__ BT,
                                                  const float* __restrict__ bias,
                                                  float* __restrict__ C) {
    gemm_body<0>(A, BT, bias, C, nullptr, nullptr, nullptr, nullptr, Dm, Dm);
}

// ---------------- stage 3: flash attention (swapped-operand, 32x32x16) ------
// R7: break the lockstep serial chains.
//  - tree reductions for row-max and row-sum (depth 31 -> 5)
//  - PV pipelined one tile back: iteration t = QK(t) | PV(t-1) | softmax(t);
//    PV's MFMA cluster is independent of softmax(t)'s chain, so the scheduler
//    interleaves them. V is TRIPLE-buffered (rotating pointers, rule #20-safe)
//    so stage(t+1) never collides with PV(t-1)'s reads. LDS 80KB/block.
//  - pack+shfl exchange issued BEFORE the sum tree (DS latency overlap).
DEV f32x16 mfma32(bf16x8 a, bf16x8 b, f32x16 c) {
    return __builtin_amdgcn_mfma_f32_32x32x16_bf16(a, b, c, 0, 0, 0);
}
DEV unsigned packbf(float lo, float hi) {
    unsigned short a = __builtin_bit_cast(unsigned short, (bf16)lo);
    unsigned short b = __builtin_bit_cast(unsigned short, (bf16)hi);
    return (unsigned)a | ((unsigned)b << 16);
}

DEV void stage_k(const char* kb, char* dst, int j0, int qw, int lane) {
#pragma unroll
    for (int c = 0; c < 2; ++c) {
        const int j = qw * 2 + c;              // chunk 0..7 (wave-uniform)
        const int rsw = lane ^ j;              // pre-swizzled source row
        __builtin_amdgcn_global_load_lds(AS1(kb + (size_t)(j0 + rsw) * 128 + j * 16),
                                         AS3(dst + j * 1024), 16, 0, 0);
    }
}
DEV void stage_v(const char* vb, char* dst, int j0, int qw, int lane) {
#pragma unroll
    for (int c = 0; c < 2; ++c) {
        const int j = qw * 2 + c;
        const int rsw = lane ^ j;
        __builtin_amdgcn_global_load_lds(AS1(vb + (size_t)rsw * 4096 + (size_t)j0 * 2 + j * 16),
                                         AS3(dst + j * 1024), 16, 0, 0);
    }
}

DEV void qk_cluster(const char* Kl, const bf16x8* qf, int l31, int hi,
                    f32x16& s0, f32x16& s1) {
    __builtin_amdgcn_s_setprio(1);
#pragma unroll
    for (int kst = 0; kst < 4; ++kst) {
        const int jK = kst * 2 + hi;
        const int x = l31 ^ jK;                // jK<8: flips low bits only
        bf16x8 ka = *(const bf16x8*)(Kl + jK * 1024 + x * 16);
        bf16x8 kc = *(const bf16x8*)(Kl + jK * 1024 + (32 + x) * 16);
        s0 = mfma32(ka, qf[kst], s0);
        s1 = mfma32(kc, qf[kst], s1);
    }
    __builtin_amdgcn_s_setprio(0);
}

DEV void pv_cluster(const char* Vl, const bf16x8 pf[2][2], int l31, int hi,
                    f32x16& o0, f32x16& o1) {
    __builtin_amdgcn_s_setprio(1);
#pragma unroll
    for (int J = 0; J < 2; ++J)
#pragma unroll
        for (int st = 0; st < 2; ++st) {
            const int jV = J * 4 + st * 2 + hi;
            const int x = l31 ^ jV;
            bf16x8 v0 = *(const bf16x8*)(Vl + jV * 1024 + x * 16);
            bf16x8 v1 = *(const bf16x8*)(Vl + jV * 1024 + (32 + x) * 16);
            o0 = mfma32(v0, pf[J][st], o0);
            o1 = mfma32(v1, pf[J][st], o1);
        }
    __builtin_amdgcn_s_setprio(0);
}

DEV void softmax_pack(f32x16& s0, f32x16& s1, f32x16& o0, f32x16& o1,
                      float& m, float& lsum, int hi, bf16x8 pf[2][2]) {
    // row-max: tree, depth 5 + cross-half shfl
    float t8[8];
#pragma unroll
    for (int i = 0; i < 8; ++i)
        t8[i] = fmaxf(fmaxf(s0[i], s0[i + 8]), fmaxf(s1[i], s1[i + 8]));
#pragma unroll
    for (int i = 0; i < 4; ++i) t8[i] = fmaxf(t8[i], t8[i + 4]);
    float pm = fmaxf(fmaxf(t8[0], t8[2]), fmaxf(t8[1], t8[3]));
    pm = fmaxf(pm, __shfl_xor(pm, 32));
    if (!__all(pm <= m + 8.0f)) {          // defer-max (T13), log2 units
        float mn = fmaxf(m, pm);
        float sc = exp2_fast(m - mn);
#pragma unroll
        for (int r = 0; r < 16; ++r) { o0[r] *= sc; o1[r] *= sc; }
        lsum *= sc; m = mn;
    }
#pragma unroll
    for (int r = 0; r < 16; ++r) s0[r] = exp2_fast(s0[r] - m);
#pragma unroll
    for (int r = 0; r < 16; ++r) s1[r] = exp2_fast(s1[r] - m);

    // pack + issue exchange shfls FIRST; sum tree runs under their latency
    unsigned u[16];
#pragma unroll
    for (int t2 = 0; t2 < 8; ++t2) {
        u[t2]     = packbf(s0[2 * t2], s0[2 * t2 + 1]);
        u[8 + t2] = packbf(s1[2 * t2], s1[2 * t2 + 1]);
    }
    unsigned snd[8], rcv[8];
#pragma unroll
    for (int J = 0; J < 2; ++J)
#pragma unroll
        for (int st = 0; st < 2; ++st) {
            const int t0 = J * 8 + st * 4, q = (J * 2 + st) * 2;
            snd[q + 0] = hi ? u[t0 + 0] : u[t0 + 2];
            snd[q + 1] = hi ? u[t0 + 1] : u[t0 + 3];
        }
#pragma unroll
    for (int t2 = 0; t2 < 8; ++t2) rcv[t2] = __shfl_xor(snd[t2], 32);

    // row-sum: tree, depth 5
    float r8[8];
#pragma unroll
    for (int i = 0; i < 8; ++i)
        r8[i] = (s0[i] + s0[i + 8]) + (s1[i] + s1[i + 8]);
#pragma unroll
    for (int i = 0; i < 4; ++i) r8[i] += r8[i + 4];
    float rs = (r8[0] + r8[2]) + (r8[1] + r8[3]);
    rs += __shfl_xor(rs, 32);
    lsum += rs;

#pragma unroll
    for (int J = 0; J < 2; ++J)
#pragma unroll
        for (int st = 0; st < 2; ++st) {
            const int t0 = J * 8 + st * 4, q = (J * 2 + st) * 2;
            union { unsigned wd[4]; bf16x8 v; } f;
            f.wd[0] = hi ? rcv[q + 0] : u[t0 + 0];
            f.wd[1] = hi ? rcv[q + 1] : u[t0 + 1];
            f.wd[2] = hi ? u[t0 + 2] : rcv[q + 0];
            f.wd[3] = hi ? u[t0 + 3] : rcv[q + 1];
            pf[J][st] = f.v;
        }
}

__global__ __launch_bounds__(512, 4) void k_attn(const bf16* __restrict__ Q,
                                                 const bf16* __restrict__ Kt,
                                                 const bf16* __restrict__ Vt,
                                                 bf16* __restrict__ Op) {
    __shared__ uint4 smem4[5120];   // 80KB: 2 halves x (K 2x8KB + V 3x8KB)
    char* base = (char*)smem4;
    const int tid = threadIdx.x;
    const int w = tid >> 6, lane = tid & 63;
    const int qw = w & 3, s = w >> 2;
    const int hi = lane >> 5, l31 = lane & 31;
    const int bid = blockIdx.x;
    const int bh = bid >> 4, qt = bid & 15;
    const int q0 = qt * 128 + qw * 32;
    const char* qb = (const char*)(Q + (size_t)bh * Lseq * 64);
    const char* kb = (const char*)(Kt + (size_t)bh * Lseq * 64);
    const char* vb = (const char*)(Vt + (size_t)bh * 64 * Lseq);
    char* setb = base + s * 40960;             // this half's pipeline
    char* Kb0 = setb;
    char* Kb1 = setb + 8192;
    char* VA = setb + 16384;
    char* VB = setb + 24576;
    char* VC = setb + 32768;
    const int jbase = s * 16;                  // this half's first tile index

    // Q frags (B-operand): elem i = Q[q0+l31][kst*16 + hi*8 + i]
    bf16x8 qf[4];
#pragma unroll
    for (int kst = 0; kst < 4; ++kst)
        qf[kst] = *(const bf16x8*)(qb + (size_t)(q0 + l31) * 128 + kst * 32 + hi * 16);

    f32x16 o0 = {}, o1 = {};
    float m = -1e30f, lsum = 0.f;
    bf16x8 pf[2][2];

    // prologue: stage tile 0 of this half
    stage_k(kb, Kb0, jbase * 64, qw, lane);
    stage_v(vb, VA, jbase * 64, qw, lane);
    __syncthreads();

    // t = 0 (peeled: no PV yet)
    {
        stage_k(kb, Kb1, (jbase + 1) * 64, qw, lane);
        stage_v(vb, VB, (jbase + 1) * 64, qw, lane);
        f32x16 a0 = {}, a1 = {};
        qk_cluster(Kb0, qf, l31, hi, a0, a1);
        softmax_pack(a0, a1, o0, o1, m, lsum, hi, pf);
        __syncthreads();
    }

    char* kcur = Kb1; char* knext = Kb0;
    char* vprev = VA; char* vcur = VB; char* vnext = VC;
#pragma unroll 1
    for (int t = 1; t < 16; ++t) {
        if (t < 15) {
            stage_k(kb, knext, (jbase + t + 1) * 64, qw, lane);
            stage_v(vb, vnext, (jbase + t + 1) * 64, qw, lane);
        }
        f32x16 a0 = {}, a1 = {};
        qk_cluster(kcur, qf, l31, hi, a0, a1);
        pv_cluster(vprev, pf, l31, hi, o0, o1);      // interleaves under softmax
        softmax_pack(a0, a1, o0, o1, m, lsum, hi, pf);
        // rotate buffers
        char* tk = kcur; kcur = knext; knext = tk;
        char* tv = vprev; vprev = vcur; vcur = vnext; vnext = tv;
        __syncthreads();
    }
    // epilogue PV for the last tile (vprev == V(15) after rotation)
    pv_cluster(vprev, pf, l31, hi, o0, o1);
    __syncthreads();

    // ---- combine the two KV halves (LDS exchange; K/V buffers now dead) ----
    float* ex = (float*)base;                   // per qw-wave region: 2176 floats
    if (s == 1) {
        float* r = ex + qw * 2176;
#pragma unroll
        for (int t = 0; t < 16; ++t) {
            r[t * 64 + lane] = o0[t];
            r[1024 + t * 64 + lane] = o1[t];
        }
        r[2048 + lane] = m;
        r[2112 + lane] = lsum;
    }
    __syncthreads();
    if (s == 0) {
        float* r = ex + qw * 2176;
        const float mb = r[2048 + lane], lb = r[2112 + lane];
        const float M = fmaxf(m, mb);
        const float wa = exp2_fast(m - M), wb = exp2_fast(mb - M);
        const float inv = 1.0f / (wa * lsum + wb * lb);
        const float fa = wa * inv, fb = wb * inv;
        const int b = bh >> 4, h = bh & 15;
        bf16* dst = Op + (size_t)(b * Lseq + q0 + l31) * Dm + h * 64;
        // epilogue layout: lane owns col q = l31; rows d = (r&3)+8*(r>>2)+4*hi
#pragma unroll
        for (int t = 0; t < 4; ++t) {
            bf16x4 p0, p1;
#pragma unroll
            for (int i = 0; i < 4; ++i) {
                p0[i] = (bf16)(o0[4 * t + i] * fa + r[(4 * t + i) * 64 + lane] * fb);
                p1[i] = (bf16)(o1[4 * t + i] * fa + r[1024 + (4 * t + i) * 64 + lane] * fb);
            }
            *(bf16x4*)(dst + 8 * t + 4 * hi) = p0;
            *(bf16x4*)(dst + 32 + 8 * t + 4 * hi) = p1;
        }
    }
}

// ---------------- launch ----------------
extern "C" void kernel_launch(void* const* d_in, const int* in_sizes, int n_in,
                              void* d_out, int out_size, void* d_ws, size_t ws_size,
                              hipStream_t stream) {
    (void)in_sizes; (void)n_in; (void)out_size; (void)ws_size;
    const float* x    = (const float*)d_in[0];
    const float* Wqkv = (const float*)d_in[1];
    const float* bqkv = (const float*)d_in[2];
    const float* Wout = (const float*)d_in[3];
    const float* bout = (const float*)d_in[4];
    float* out = (float*)d_out;
    char* ws = (char*)d_ws;

    bf16* xbf    = (bf16*)(ws + OFF_XATT);
    bf16* att    = (bf16*)(ws + OFF_XATT);   // aliases xbf (dead after gemm_qkv)
    bf16* wqkvT  = (bf16*)(ws + OFF_WQKVT);
    bf16* woutT  = (bf16*)(ws + OFF_WOUTT);
    float2* tab  = (float2*)(ws + OFF_TAB);
    bf16* qb     = (bf16*)(ws + OFF_Q);
    bf16* kb     = (bf16*)(ws + OFF_K);
    bf16* vt     = (bf16*)(ws + OFF_VT);

    hipLaunchKernelGGL(k_convert, dim3((BL * Dm) / 8 / 256), dim3(256), 0, stream, x, xbf);
    hipLaunchKernelGGL(k_transpose, dim3(TN / 32, Dm / 32), dim3(32, 8), 0, stream, Wqkv, wqkvT, Dm, TN);
    hipLaunchKernelGGL(k_transpose, dim3(Dm / 32, Dm / 32), dim3(32, 8), 0, stream, Wout, woutT, Dm, Dm);
    hipLaunchKernelGGL(k_sincos, dim3(Lseq * 32 / 256), dim3(256), 0, stream, tab);
    hipLaunchKernelGGL(k_gemm_qkv, dim3(TN / 128, BL / 128), dim3(256), 0, stream,
                       xbf, wqkvT, bqkv, qb, kb, vt, tab);
    hipLaunchKernelGGL(k_attn, dim3(32 * 16), dim3(512), 0, stream, qb, kb, vt, att);
    hipLaunchKernelGGL(k_gemm_out, dim3(Dm / 128, BL / 128), dim3(256), 0, stream,
                       att, woutT, bout, out);
}

// Round 8
// 150.862 us; speedup vs baseline: 1.0615x; 1.0615x over previous
//
#include <hip/hip_runtime.h>
#include <hip/hip_bf16.h>
#include <math.h>

typedef __bf16 bf16;
typedef __bf16 bf16x8 __attribute__((ext_vector_type(8)));
typedef __bf16 bf16x4 __attribute__((ext_vector_type(4)));
typedef float f32x4 __attribute__((ext_vector_type(4)));
typedef float f32x16 __attribute__((ext_vector_type(16)));

#define DEV __device__ __forceinline__
#define AS1(p) ((const __attribute__((address_space(1))) void*)(p))
#define AS3(p) ((__attribute__((address_space(3))) void*)(p))

// ---------------- problem sizes ----------------
#define Bsz 2
#define Lseq 2048
#define Dm 1024
#define Hh 16
#define HD 64
#define BL (Bsz * Lseq)   // 4096 rows
#define TN (3 * Dm)       // 3072

#define LOG2E 1.44269504088896f

// ---------------- workspace layout (bytes) ----------------
#define OFF_XATT  ((size_t)0)                            // xbf bf16 8.39MB; att aliases after gemm1
#define OFF_WQKVT (OFF_XATT  + (size_t)BL * Dm * 2)      // 6.29MB
#define OFF_WOUTT (OFF_WQKVT + (size_t)TN * Dm * 2)      // 2.10MB
#define OFF_TAB   (OFF_WOUTT + (size_t)Dm * Dm * 2)      // 0.52MB
#define OFF_Q     (OFF_TAB   + (size_t)Lseq * 32 * 8)    // 8.39MB q bf16 [32][2048][64]
#define OFF_K     (OFF_Q     + (size_t)BL * Dm * 2)      // 8.39MB
#define OFF_VT    (OFF_K     + (size_t)BL * Dm * 2)      // 8.39MB vT bf16 [32][64][2048]
// end = 42.5 MB

DEV float exp2_fast(float x) {   // 2^x, single v_exp_f32
    float r;
    asm("v_exp_f32 %0, %1" : "=v"(r) : "v"(x));
    return r;
}

// ---------------- stage 0: convert x to bf16 ----------------
__global__ __launch_bounds__(256) void k_convert(const float* __restrict__ in,
                                                 bf16* __restrict__ out) {
    int i = blockIdx.x * 256 + threadIdx.x;
    const float4* in4 = (const float4*)in;
    float4 a = in4[i * 2];
    float4 b = in4[i * 2 + 1];
    bf16x8 o;
    o[0] = (bf16)a.x; o[1] = (bf16)a.y; o[2] = (bf16)a.z; o[3] = (bf16)a.w;
    o[4] = (bf16)b.x; o[5] = (bf16)b.y; o[6] = (bf16)b.z; o[7] = (bf16)b.w;
    ((bf16x8*)out)[i] = o;
}

// ---------------- stage 0b: transpose fp32 [R][C] -> bf16 [C][R] ----------------
__global__ __launch_bounds__(256) void k_transpose(const float* __restrict__ in,
                                                   bf16* __restrict__ out,
                                                   int R, int C) {
    __shared__ float t[32][33];
    int bx = blockIdx.x * 32;
    int by = blockIdx.y * 32;
    int tx = threadIdx.x, ty = threadIdx.y;
#pragma unroll
    for (int i = 0; i < 32; i += 8)
        t[ty + i][tx] = in[(size_t)(by + ty + i) * C + bx + tx];
    __syncthreads();
#pragma unroll
    for (int i = 0; i < 32; i += 8)
        out[(size_t)(bx + ty + i) * R + by + tx] = (bf16)t[tx][ty + i];
}

// ---------------- stage 0c: sin/cos table [2048][32] {sin,cos} ----------------
__global__ __launch_bounds__(256) void k_sincos(float2* __restrict__ tab) {
    int idx = blockIdx.x * 256 + threadIdx.x;
    int pos = idx >> 5, t = idx & 31;
    float theta = powf(10000.0f, -(float)t * (1.0f / 32.0f));
    float f = (float)pos * theta;
    tab[idx] = make_float2(sinf(f), cosf(f));
}

// ---------------- bf16 GEMM, 128x128 tile, BK=64 ----------------
// global_load_lds staging (rule #21 both-sides swizzle); full-unrolled
// epilogues (rule #20). R8: 1D grid + bijective XCD-chunk swizzle (T1):
// each XCD gets contiguous output rows -> A-panel L2 reuse.
template <int EPI>
DEV void gemm_body(const bf16* __restrict__ A,
                   const bf16* __restrict__ BT,
                   const float* __restrict__ bias,
                   float* __restrict__ C,
                   bf16* __restrict__ qo,
                   bf16* __restrict__ ko,
                   bf16* __restrict__ vt,
                   const float2* __restrict__ tab,
                   int m0, int n0, int N, int K) {
    __shared__ uint4 smem4[2048];   // 32KB: A tile 16KB + B tile 16KB
    char* Al = (char*)smem4;
    char* Bl = (char*)smem4 + 16384;
    const int tid = threadIdx.x;
    const int w = tid >> 6, lane = tid & 63, lg = lane >> 4, lr = lane & 15;
    const int wm = (w >> 1) * 64, wn = (w & 1) * 64;
    const char* Ab = (const char*)A;
    const char* Bb = (const char*)BT;
    const size_t Kb = (size_t)K * 2;

    f32x4 acc[4][4] = {};

    const int rowL = lane >> 3;                    // 0..7 within 8-row group
    const int j16 = ((lane & 7) ^ rowL) * 16;      // pre-swizzled source chunk byte

    for (int kt = 0; kt < K; kt += 64) {
#pragma unroll
        for (int c = 0; c < 4; ++c) {
            const int R0 = (w * 4 + c) * 8;
            const int row = R0 + rowL;
            __builtin_amdgcn_global_load_lds(AS1(Ab + (size_t)(m0 + row) * Kb + kt * 2 + j16),
                                             AS3(Al + R0 * 128), 16, 0, 0);
            __builtin_amdgcn_global_load_lds(AS1(Bb + (size_t)(n0 + row) * Kb + kt * 2 + j16),
                                             AS3(Bl + R0 * 128), 16, 0, 0);
        }
        __syncthreads();
#pragma unroll
        for (int kf = 0; kf < 2; ++kf) {
            bf16x8 af[4], bfr[4];
#pragma unroll
            for (int i = 0; i < 4; ++i) {
                int ra = wm + i * 16 + lr;
                af[i] = *(const bf16x8*)(Al + ra * 128 + ((kf * 64 + lg * 16) ^ ((ra & 7) << 4)));
                int rb = wn + i * 16 + lr;
                bfr[i] = *(const bf16x8*)(Bl + rb * 128 + ((kf * 64 + lg * 16) ^ ((rb & 7) << 4)));
            }
#pragma unroll
            for (int i = 0; i < 4; ++i)
#pragma unroll
                for (int j = 0; j < 4; ++j)
                    acc[i][j] = __builtin_amdgcn_mfma_f32_16x16x32_bf16(af[i], bfr[j], acc[i][j], 0, 0, 0);
        }
        __syncthreads();
    }

    if constexpr (EPI == 0) {
#pragma unroll
        for (int i = 0; i < 4; ++i) {
            int row = m0 + wm + i * 16 + lg * 4;
#pragma unroll
            for (int j = 0; j < 4; ++j) {
                int col = n0 + wn + j * 16 + lr;
                float bv = bias[col];
#pragma unroll
                for (int r = 0; r < 4; ++r)
                    C[(size_t)(row + r) * N + col] = acc[i][j][r] + bv;
            }
        }
    } else {
        const int phase = n0 >> 10;            // 0=q 1=k 2=v
        const int c0 = n0 + wn;
        const int h = (c0 & 1023) >> 6;
        const int b = m0 >> 11;
        const int bh = b * 16 + h;
        const int lbase = (m0 & 2047) + wm;
        float bv[4];
#pragma unroll
        for (int j = 0; j < 4; ++j) bv[j] = bias[c0 + j * 16 + lr];
        float* Lw = (float*)((char*)smem4 + w * 4096);

#pragma unroll   // FULL unroll: compile-time acc indices (rule #20)
        for (int i = 0; i < 4; ++i) {
#pragma unroll
            for (int j = 0; j < 4; ++j)
#pragma unroll
                for (int r = 0; r < 4; ++r)
                    Lw[(lg * 4 + r) * 64 + j * 16 + lr] = acc[i][j][r] + bv[j];
            __syncthreads();
            if (phase < 2) {
                // q gets 1/8 (scores) * log2e (exp2-domain softmax) folded in
                const float scale = (phase == 0) ? 0.125f * LOG2E : 1.0f;
                bf16* dst = (phase == 0 ? qo : ko) + (size_t)bh * Lseq * 64;
#pragma unroll
                for (int j = 0; j < 4; ++j)
#pragma unroll
                    for (int r = 0; r < 4; ++r) {
                        int rl = lg * 4 + r;
                        int d = j * 16 + lr;
                        int l = lbase + i * 16 + rl;
                        float v = Lw[rl * 64 + d];
                        int dp = (d < 32) ? (2 * d + 1) : (2 * d - 64);
                        float p = Lw[rl * 64 + dp];
                        float2 f = tab[l * 32 + (d & 31)];
                        float val = ((d < 32) ? (v - p) * f.x : (v + p) * f.y) * scale;
                        dst[(size_t)l * 64 + d] = (bf16)val;
                    }
            } else {
                int d = lane;
                int lb = lbase + i * 16;
                bf16x8 o1, o2;
#pragma unroll
                for (int rw = 0; rw < 8; ++rw) {
                    o1[rw] = (bf16)Lw[rw * 64 + d];
                    o2[rw] = (bf16)Lw[(rw + 8) * 64 + d];
                }
                bf16* dst = vt + ((size_t)bh * 64 + d) * Lseq + lb;
                *(bf16x8*)dst = o1;
                *(bf16x8*)(dst + 8) = o2;
            }
            __syncthreads();
        }
    }
}

// XCD-chunk swizzle: nwg % 8 == 0 (768 / 256), bijective.
DEV void xcd_tile(int nx, int nwg, int& m0, int& n0) {
    int id = blockIdx.x;
    int id2 = (id & 7) * (nwg >> 3) + (id >> 3);
    n0 = (id2 % nx) * 128;
    m0 = (id2 / nx) * 128;
}

__global__ __launch_bounds__(256) void k_gemm_qkv(const bf16* __restrict__ A,
                                                  const bf16* __restrict__ BT,
                                                  const float* __restrict__ bias,
                                                  bf16* __restrict__ qo,
                                                  bf16* __restrict__ ko,
                                                  bf16* __restrict__ vt,
                                                  const float2* __restrict__ tab) {
    int m0, n0;
    xcd_tile(TN / 128, (TN / 128) * (BL / 128), m0, n0);
    gemm_body<1>(A, BT, bias, nullptr, qo, ko, vt, tab, m0, n0, TN, Dm);
}
__global__ __launch_bounds__(256) void k_gemm_out(const bf16* __restrict__ A,
                                                  const bf16* __restrict__ BT,
                                                  const float* __restrict__ bias,
                                                  float* __restrict__ C) {
    int m0, n0;
    xcd_tile(Dm / 128, (Dm / 128) * (BL / 128), m0, n0);
    gemm_body<0>(A, BT, bias, C, nullptr, nullptr, nullptr, nullptr, m0, n0, Dm, Dm);
}

// ---------------- stage 3: flash attention (swapped-operand, 32x32x16) ------
// R8: R6 schedule restored (QK -> softmax -> PV same tile, one barrier,
// double-buffered K/V, 64KB LDS) with the loop unrolled x2 EXPLICITLY over
// static buffer objects (R7 post-mortem: runtime-rotated pointers +
// unroll-1 blocked compiler scheduling and regressed 33%).
// Kept from R7: tree reductions (depth 5), exchange shfls issued before the
// sum tree. New: blockIdx remap concentrating each head's 16 blocks on one
// XCD (4 heads x 512KB KV = 2MB < 4MB L2).
DEV f32x16 mfma32(bf16x8 a, bf16x8 b, f32x16 c) {
    return __builtin_amdgcn_mfma_f32_32x32x16_bf16(a, b, c, 0, 0, 0);
}
DEV unsigned packbf(float lo, float hi) {
    unsigned short a = __builtin_bit_cast(unsigned short, (bf16)lo);
    unsigned short b = __builtin_bit_cast(unsigned short, (bf16)hi);
    return (unsigned)a | ((unsigned)b << 16);
}

DEV void stage_k(const char* kb, char* dst, int j0, int qw, int lane) {
#pragma unroll
    for (int c = 0; c < 2; ++c) {
        const int j = qw * 2 + c;              // chunk 0..7 (wave-uniform)
        const int rsw = lane ^ j;              // pre-swizzled source row
        __builtin_amdgcn_global_load_lds(AS1(kb + (size_t)(j0 + rsw) * 128 + j * 16),
                                         AS3(dst + j * 1024), 16, 0, 0);
    }
}
DEV void stage_v(const char* vb, char* dst, int j0, int qw, int lane) {
#pragma unroll
    for (int c = 0; c < 2; ++c) {
        const int j = qw * 2 + c;
        const int rsw = lane ^ j;
        __builtin_amdgcn_global_load_lds(AS1(vb + (size_t)rsw * 4096 + (size_t)j0 * 2 + j * 16),
                                         AS3(dst + j * 1024), 16, 0, 0);
    }
}

DEV void qk_cluster(const char* Kl, const bf16x8* qf, int l31, int hi,
                    f32x16& s0, f32x16& s1) {
    __builtin_amdgcn_s_setprio(1);
#pragma unroll
    for (int kst = 0; kst < 4; ++kst) {
        const int jK = kst * 2 + hi;
        const int x = l31 ^ jK;                // jK<8: flips low bits only
        bf16x8 ka = *(const bf16x8*)(Kl + jK * 1024 + x * 16);
        bf16x8 kc = *(const bf16x8*)(Kl + jK * 1024 + (32 + x) * 16);
        s0 = mfma32(ka, qf[kst], s0);
        s1 = mfma32(kc, qf[kst], s1);
    }
    __builtin_amdgcn_s_setprio(0);
}

DEV void pv_cluster(const char* Vl, const bf16x8 pf[2][2], int l31, int hi,
                    f32x16& o0, f32x16& o1) {
    __builtin_amdgcn_s_setprio(1);
#pragma unroll
    for (int J = 0; J < 2; ++J)
#pragma unroll
        for (int st = 0; st < 2; ++st) {
            const int jV = J * 4 + st * 2 + hi;
            const int x = l31 ^ jV;
            bf16x8 v0 = *(const bf16x8*)(Vl + jV * 1024 + x * 16);
            bf16x8 v1 = *(const bf16x8*)(Vl + jV * 1024 + (32 + x) * 16);
            o0 = mfma32(v0, pf[J][st], o0);
            o1 = mfma32(v1, pf[J][st], o1);
        }
    __builtin_amdgcn_s_setprio(0);
}

DEV void softmax_pack(f32x16& s0, f32x16& s1, f32x16& o0, f32x16& o1,
                      float& m, float& lsum, int hi, bf16x8 pf[2][2]) {
    // row-max: tree, depth 5 + cross-half shfl
    float t8[8];
#pragma unroll
    for (int i = 0; i < 8; ++i)
        t8[i] = fmaxf(fmaxf(s0[i], s0[i + 8]), fmaxf(s1[i], s1[i + 8]));
#pragma unroll
    for (int i = 0; i < 4; ++i) t8[i] = fmaxf(t8[i], t8[i + 4]);
    float pm = fmaxf(fmaxf(t8[0], t8[2]), fmaxf(t8[1], t8[3]));
    pm = fmaxf(pm, __shfl_xor(pm, 32));
    if (!__all(pm <= m + 8.0f)) {          // defer-max (T13), log2 units
        float mn = fmaxf(m, pm);
        float sc = exp2_fast(m - mn);
#pragma unroll
        for (int r = 0; r < 16; ++r) { o0[r] *= sc; o1[r] *= sc; }
        lsum *= sc; m = mn;
    }
#pragma unroll
    for (int r = 0; r < 16; ++r) s0[r] = exp2_fast(s0[r] - m);
#pragma unroll
    for (int r = 0; r < 16; ++r) s1[r] = exp2_fast(s1[r] - m);

    // pack + issue exchange shfls FIRST; sum tree runs under their latency
    unsigned u[16];
#pragma unroll
    for (int t2 = 0; t2 < 8; ++t2) {
        u[t2]     = packbf(s0[2 * t2], s0[2 * t2 + 1]);
        u[8 + t2] = packbf(s1[2 * t2], s1[2 * t2 + 1]);
    }
    unsigned snd[8], rcv[8];
#pragma unroll
    for (int J = 0; J < 2; ++J)
#pragma unroll
        for (int st = 0; st < 2; ++st) {
            const int t0 = J * 8 + st * 4, q = (J * 2 + st) * 2;
            snd[q + 0] = hi ? u[t0 + 0] : u[t0 + 2];
            snd[q + 1] = hi ? u[t0 + 1] : u[t0 + 3];
        }
#pragma unroll
    for (int t2 = 0; t2 < 8; ++t2) rcv[t2] = __shfl_xor(snd[t2], 32);

    // row-sum: tree, depth 5
    float r8[8];
#pragma unroll
    for (int i = 0; i < 8; ++i)
        r8[i] = (s0[i] + s0[i + 8]) + (s1[i] + s1[i + 8]);
#pragma unroll
    for (int i = 0; i < 4; ++i) r8[i] += r8[i + 4];
    float rs = (r8[0] + r8[2]) + (r8[1] + r8[3]);
    rs += __shfl_xor(rs, 32);
    lsum += rs;

#pragma unroll
    for (int J = 0; J < 2; ++J)
#pragma unroll
        for (int st = 0; st < 2; ++st) {
            const int t0 = J * 8 + st * 4, q = (J * 2 + st) * 2;
            union { unsigned wd[4]; bf16x8 v; } f;
            f.wd[0] = hi ? rcv[q + 0] : u[t0 + 0];
            f.wd[1] = hi ? rcv[q + 1] : u[t0 + 1];
            f.wd[2] = hi ? u[t0 + 2] : rcv[q + 0];
            f.wd[3] = hi ? u[t0 + 3] : rcv[q + 1];
            pf[J][st] = f.v;
        }
}

__global__ __launch_bounds__(512, 4) void k_attn(const bf16* __restrict__ Q,
                                                 const bf16* __restrict__ Kt,
                                                 const bf16* __restrict__ Vt,
                                                 bf16* __restrict__ Op) {
    __shared__ uint4 smem4[4096];   // 64KB: 2 halves x (K0,K1,V0,V1 x 8KB)
    char* base = (char*)smem4;
    const int tid = threadIdx.x;
    const int w = tid >> 6, lane = tid & 63;
    const int qw = w & 3, s = w >> 2;
    const int hi = lane >> 5, l31 = lane & 31;
    // blockIdx remap: 16 blocks of one head -> same XCD (KV L2-resident)
    const int i0 = blockIdx.x;
    const int bh = (i0 & 7) * 4 + ((i0 >> 3) >> 4);
    const int qt = (i0 >> 3) & 15;
    const int q0 = qt * 128 + qw * 32;
    const char* qb = (const char*)(Q + (size_t)bh * Lseq * 64);
    const char* kb = (const char*)(Kt + (size_t)bh * Lseq * 64);
    const char* vb = (const char*)(Vt + (size_t)bh * 64 * Lseq);
    char* setb = base + s * 32768;             // this half's pipeline
    char* const K0 = setb;
    char* const K1 = setb + 8192;
    char* const V0 = setb + 16384;
    char* const V1 = setb + 24576;
    const int jbase = s * 16;                  // this half's first tile index

    // Q frags (B-operand): elem i = Q[q0+l31][kst*16 + hi*8 + i]
    bf16x8 qf[4];
#pragma unroll
    for (int kst = 0; kst < 4; ++kst)
        qf[kst] = *(const bf16x8*)(qb + (size_t)(q0 + l31) * 128 + kst * 32 + hi * 16);

    f32x16 o0 = {}, o1 = {};
    float m = -1e30f, lsum = 0.f;
    bf16x8 pf[2][2];

    // prologue: stage tile 0 of this half into buf 0
    stage_k(kb, K0, jbase * 64, qw, lane);
    stage_v(vb, V0, jbase * 64, qw, lane);
    __syncthreads();

#pragma unroll 1
    for (int tt = 0; tt < 8; ++tt) {
        const int t = tt * 2;
        // even phase: consume buf0, stage t+1 into buf1
        stage_k(kb, K1, (jbase + t + 1) * 64, qw, lane);
        stage_v(vb, V1, (jbase + t + 1) * 64, qw, lane);
        {
            f32x16 a0 = {}, a1 = {};
            qk_cluster(K0, qf, l31, hi, a0, a1);
            softmax_pack(a0, a1, o0, o1, m, lsum, hi, pf);
            pv_cluster(V0, pf, l31, hi, o0, o1);
        }
        __syncthreads();
        // odd phase: consume buf1, stage t+2 into buf0
        if (tt < 7) {
            stage_k(kb, K0, (jbase + t + 2) * 64, qw, lane);
            stage_v(vb, V0, (jbase + t + 2) * 64, qw, lane);
        }
        {
            f32x16 a0 = {}, a1 = {};
            qk_cluster(K1, qf, l31, hi, a0, a1);
            softmax_pack(a0, a1, o0, o1, m, lsum, hi, pf);
            pv_cluster(V1, pf, l31, hi, o0, o1);
        }
        __syncthreads();
    }

    // ---- combine the two KV halves (LDS exchange; K/V buffers now dead) ----
    float* ex = (float*)base;                   // per qw-wave region: 2176 floats
    if (s == 1) {
        float* r = ex + qw * 2176;
#pragma unroll
        for (int t = 0; t < 16; ++t) {
            r[t * 64 + lane] = o0[t];
            r[1024 + t * 64 + lane] = o1[t];
        }
        r[2048 + lane] = m;
        r[2112 + lane] = lsum;
    }
    __syncthreads();
    if (s == 0) {
        float* r = ex + qw * 2176;
        const float mb = r[2048 + lane], lb = r[2112 + lane];
        const float M = fmaxf(m, mb);
        const float wa = exp2_fast(m - M), wb = exp2_fast(mb - M);
        const float inv = 1.0f / (wa * lsum + wb * lb);
        const float fa = wa * inv, fb = wb * inv;
        const int b = bh >> 4, h = bh & 15;
        bf16* dst = Op + (size_t)(b * Lseq + q0 + l31) * Dm + h * 64;
        // epilogue layout: lane owns col q = l31; rows d = (r&3)+8*(r>>2)+4*hi
#pragma unroll
        for (int t = 0; t < 4; ++t) {
            bf16x4 p0, p1;
#pragma unroll
            for (int i = 0; i < 4; ++i) {
                p0[i] = (bf16)(o0[4 * t + i] * fa + r[(4 * t + i) * 64 + lane] * fb);
                p1[i] = (bf16)(o1[4 * t + i] * fa + r[1024 + (4 * t + i) * 64 + lane] * fb);
            }
            *(bf16x4*)(dst + 8 * t + 4 * hi) = p0;
            *(bf16x4*)(dst + 32 + 8 * t + 4 * hi) = p1;
        }
    }
}

// ---------------- launch ----------------
extern "C" void kernel_launch(void* const* d_in, const int* in_sizes, int n_in,
                              void* d_out, int out_size, void* d_ws, size_t ws_size,
                              hipStream_t stream) {
    (void)in_sizes; (void)n_in; (void)out_size; (void)ws_size;
    const float* x    = (const float*)d_in[0];
    const float* Wqkv = (const float*)d_in[1];
    const float* bqkv = (const float*)d_in[2];
    const float* Wout = (const float*)d_in[3];
    const float* bout = (const float*)d_in[4];
    float* out = (float*)d_out;
    char* ws = (char*)d_ws;

    bf16* xbf    = (bf16*)(ws + OFF_XATT);
    bf16* att    = (bf16*)(ws + OFF_XATT);   // aliases xbf (dead after gemm_qkv)
    bf16* wqkvT  = (bf16*)(ws + OFF_WQKVT);
    bf16* woutT  = (bf16*)(ws + OFF_WOUTT);
    float2* tab  = (float2*)(ws + OFF_TAB);
    bf16* qb     = (bf16*)(ws + OFF_Q);
    bf16* kb     = (bf16*)(ws + OFF_K);
    bf16* vt     = (bf16*)(ws + OFF_VT);

    hipLaunchKernelGGL(k_convert, dim3((BL * Dm) / 8 / 256), dim3(256), 0, stream, x, xbf);
    hipLaunchKernelGGL(k_transpose, dim3(TN / 32, Dm / 32), dim3(32, 8), 0, stream, Wqkv, wqkvT, Dm, TN);
    hipLaunchKernelGGL(k_transpose, dim3(Dm / 32, Dm / 32), dim3(32, 8), 0, stream, Wout, woutT, Dm, Dm);
    hipLaunchKernelGGL(k_sincos, dim3(Lseq * 32 / 256), dim3(256), 0, stream, tab);
    hipLaunchKernelGGL(k_gemm_qkv, dim3((TN / 128) * (BL / 128)), dim3(256), 0, stream,
                       xbf, wqkvT, bqkv, qb, kb, vt, tab);
    hipLaunchKernelGGL(k_attn, dim3(32 * 16), dim3(512), 0, stream, qb, kb, vt, att);
    hipLaunchKernelGGL(k_gemm_out, dim3((Dm / 128) * (BL / 128)), dim3(256), 0, stream,
                       att, woutT, bout, out);
}

// Round 10
// 137.457 us; speedup vs baseline: 1.1651x; 1.0975x over previous
//
#include <hip/hip_runtime.h>
#include <hip/hip_bf16.h>
#include <math.h>

typedef __bf16 bf16;
typedef __bf16 bf16x8 __attribute__((ext_vector_type(8)));
typedef __bf16 bf16x4 __attribute__((ext_vector_type(4)));
typedef float f32x4 __attribute__((ext_vector_type(4)));
typedef float f32x16 __attribute__((ext_vector_type(16)));

#define DEV __device__ __forceinline__
#define AS1(p) ((const __attribute__((address_space(1))) void*)(p))
#define AS3(p) ((__attribute__((address_space(3))) void*)(p))

// ---------------- problem sizes ----------------
#define Bsz 2
#define Lseq 2048
#define Dm 1024
#define Hh 16
#define HD 64
#define BL (Bsz * Lseq)   // 4096 rows
#define TN (3 * Dm)       // 3072

#define LOG2E 1.44269504088896f

// ---------------- workspace layout (bytes) ----------------
#define OFF_XATT  ((size_t)0)                            // xbf bf16 8.39MB; att aliases after gemm1
#define OFF_WQKVT (OFF_XATT  + (size_t)BL * Dm * 2)      // 6.29MB
#define OFF_WOUTT (OFF_WQKVT + (size_t)TN * Dm * 2)      // 2.10MB
#define OFF_TAB   (OFF_WOUTT + (size_t)Dm * Dm * 2)      // 0.52MB
#define OFF_Q     (OFF_TAB   + (size_t)Lseq * 32 * 8)    // 8.39MB q bf16 [32][2048][64]
#define OFF_K     (OFF_Q     + (size_t)BL * Dm * 2)      // 8.39MB
#define OFF_VT    (OFF_K     + (size_t)BL * Dm * 2)      // 8.39MB vT bf16 [32][64][2048]
// end = 42.5 MB

DEV float exp2_fast(float x) {   // 2^x, single v_exp_f32
    float r;
    asm("v_exp_f32 %0, %1" : "=v"(r) : "v"(x));
    return r;
}
// v_permlane32_swap_b32 a,b: a = {a.lo, b.lo}, b = {a.hi, b.hi}.
// ONLY safe when a and b hold DISTINCT live values -- two "+v" operands
// initialized to the same value may be coalesced into ONE register
// (R9 post-mortem: v_permlane32_swap v5,v5 garbled the reductions).
DEV void plswap(unsigned& a, unsigned& b) {
    asm("v_permlane32_swap_b32 %0, %1" : "+v"(a), "+v"(b));
}

// ---------------- stage 0: convert x to bf16 ----------------
__global__ __launch_bounds__(256) void k_convert(const float* __restrict__ in,
                                                 bf16* __restrict__ out) {
    int i = blockIdx.x * 256 + threadIdx.x;
    const float4* in4 = (const float4*)in;
    float4 a = in4[i * 2];
    float4 b = in4[i * 2 + 1];
    bf16x8 o;
    o[0] = (bf16)a.x; o[1] = (bf16)a.y; o[2] = (bf16)a.z; o[3] = (bf16)a.w;
    o[4] = (bf16)b.x; o[5] = (bf16)b.y; o[6] = (bf16)b.z; o[7] = (bf16)b.w;
    ((bf16x8*)out)[i] = o;
}

// ---------------- stage 0b: transpose fp32 [R][C] -> bf16 [C][R] ----------------
__global__ __launch_bounds__(256) void k_transpose(const float* __restrict__ in,
                                                   bf16* __restrict__ out,
                                                   int R, int C) {
    __shared__ float t[32][33];
    int bx = blockIdx.x * 32;
    int by = blockIdx.y * 32;
    int tx = threadIdx.x, ty = threadIdx.y;
#pragma unroll
    for (int i = 0; i < 32; i += 8)
        t[ty + i][tx] = in[(size_t)(by + ty + i) * C + bx + tx];
    __syncthreads();
#pragma unroll
    for (int i = 0; i < 32; i += 8)
        out[(size_t)(bx + ty + i) * R + by + tx] = (bf16)t[tx][ty + i];
}

// ---------------- stage 0c: sin/cos table [2048][32] {sin,cos} ----------------
__global__ __launch_bounds__(256) void k_sincos(float2* __restrict__ tab) {
    int idx = blockIdx.x * 256 + threadIdx.x;
    int pos = idx >> 5, t = idx & 31;
    float theta = powf(10000.0f, -(float)t * (1.0f / 32.0f));
    float f = (float)pos * theta;
    tab[idx] = make_float2(sinf(f), cosf(f));
}

// ---------------- bf16 GEMM, 128x128 tile, BK=64 ----------------
// global_load_lds staging (rule #21 both-sides swizzle); full-unrolled
// epilogues (rule #20). 1D grid + bijective XCD-chunk swizzle (T1) --
// measured -4.4us on the GEMM pair in R8.
template <int EPI>
DEV void gemm_body(const bf16* __restrict__ A,
                   const bf16* __restrict__ BT,
                   const float* __restrict__ bias,
                   float* __restrict__ C,
                   bf16* __restrict__ qo,
                   bf16* __restrict__ ko,
                   bf16* __restrict__ vt,
                   const float2* __restrict__ tab,
                   int m0, int n0, int N, int K) {
    __shared__ uint4 smem4[2048];   // 32KB: A tile 16KB + B tile 16KB
    char* Al = (char*)smem4;
    char* Bl = (char*)smem4 + 16384;
    const int tid = threadIdx.x;
    const int w = tid >> 6, lane = tid & 63, lg = lane >> 4, lr = lane & 15;
    const int wm = (w >> 1) * 64, wn = (w & 1) * 64;
    const char* Ab = (const char*)A;
    const char* Bb = (const char*)BT;
    const size_t Kb = (size_t)K * 2;

    f32x4 acc[4][4] = {};

    const int rowL = lane >> 3;                    // 0..7 within 8-row group
    const int j16 = ((lane & 7) ^ rowL) * 16;      // pre-swizzled source chunk byte

    for (int kt = 0; kt < K; kt += 64) {
#pragma unroll
        for (int c = 0; c < 4; ++c) {
            const int R0 = (w * 4 + c) * 8;
            const int row = R0 + rowL;
            __builtin_amdgcn_global_load_lds(AS1(Ab + (size_t)(m0 + row) * Kb + kt * 2 + j16),
                                             AS3(Al + R0 * 128), 16, 0, 0);
            __builtin_amdgcn_global_load_lds(AS1(Bb + (size_t)(n0 + row) * Kb + kt * 2 + j16),
                                             AS3(Bl + R0 * 128), 16, 0, 0);
        }
        __syncthreads();
#pragma unroll
        for (int kf = 0; kf < 2; ++kf) {
            bf16x8 af[4], bfr[4];
#pragma unroll
            for (int i = 0; i < 4; ++i) {
                int ra = wm + i * 16 + lr;
                af[i] = *(const bf16x8*)(Al + ra * 128 + ((kf * 64 + lg * 16) ^ ((ra & 7) << 4)));
                int rb = wn + i * 16 + lr;
                bfr[i] = *(const bf16x8*)(Bl + rb * 128 + ((kf * 64 + lg * 16) ^ ((rb & 7) << 4)));
            }
#pragma unroll
            for (int i = 0; i < 4; ++i)
#pragma unroll
                for (int j = 0; j < 4; ++j)
                    acc[i][j] = __builtin_amdgcn_mfma_f32_16x16x32_bf16(af[i], bfr[j], acc[i][j], 0, 0, 0);
        }
        __syncthreads();
    }

    if constexpr (EPI == 0) {
#pragma unroll
        for (int i = 0; i < 4; ++i) {
            int row = m0 + wm + i * 16 + lg * 4;
#pragma unroll
            for (int j = 0; j < 4; ++j) {
                int col = n0 + wn + j * 16 + lr;
                float bv = bias[col];
#pragma unroll
                for (int r = 0; r < 4; ++r)
                    C[(size_t)(row + r) * N + col] = acc[i][j][r] + bv;
            }
        }
    } else {
        const int phase = n0 >> 10;            // 0=q 1=k 2=v
        const int c0 = n0 + wn;
        const int h = (c0 & 1023) >> 6;
        const int b = m0 >> 11;
        const int bh = b * 16 + h;
        const int lbase = (m0 & 2047) + wm;
        float bv[4];
#pragma unroll
        for (int j = 0; j < 4; ++j) bv[j] = bias[c0 + j * 16 + lr];
        float* Lw = (float*)((char*)smem4 + w * 4096);

#pragma unroll   // FULL unroll: compile-time acc indices (rule #20)
        for (int i = 0; i < 4; ++i) {
#pragma unroll
            for (int j = 0; j < 4; ++j)
#pragma unroll
                for (int r = 0; r < 4; ++r)
                    Lw[(lg * 4 + r) * 64 + j * 16 + lr] = acc[i][j][r] + bv[j];
            __syncthreads();
            if (phase < 2) {
                // q gets 1/8 (scores) * log2e (exp2-domain softmax) folded in
                const float scale = (phase == 0) ? 0.125f * LOG2E : 1.0f;
                bf16* dst = (phase == 0 ? qo : ko) + (size_t)bh * Lseq * 64;
#pragma unroll
                for (int j = 0; j < 4; ++j)
#pragma unroll
                    for (int r = 0; r < 4; ++r) {
                        int rl = lg * 4 + r;
                        int d = j * 16 + lr;
                        int l = lbase + i * 16 + rl;
                        float v = Lw[rl * 64 + d];
                        int dp = (d < 32) ? (2 * d + 1) : (2 * d - 64);
                        float p = Lw[rl * 64 + dp];
                        float2 f = tab[l * 32 + (d & 31)];
                        float val = ((d < 32) ? (v - p) * f.x : (v + p) * f.y) * scale;
                        dst[(size_t)l * 64 + d] = (bf16)val;
                    }
            } else {
                int d = lane;
                int lb = lbase + i * 16;
                bf16x8 o1, o2;
#pragma unroll
                for (int rw = 0; rw < 8; ++rw) {
                    o1[rw] = (bf16)Lw[rw * 64 + d];
                    o2[rw] = (bf16)Lw[(rw + 8) * 64 + d];
                }
                bf16* dst = vt + ((size_t)bh * 64 + d) * Lseq + lb;
                *(bf16x8*)dst = o1;
                *(bf16x8*)(dst + 8) = o2;
            }
            __syncthreads();
        }
    }
}

// XCD-chunk swizzle: nwg % 8 == 0 (768 / 256), bijective.
DEV void xcd_tile(int nx, int nwg, int& m0, int& n0) {
    int id = blockIdx.x;
    int id2 = (id & 7) * (nwg >> 3) + (id >> 3);
    n0 = (id2 % nx) * 128;
    m0 = (id2 / nx) * 128;
}

__global__ __launch_bounds__(256) void k_gemm_qkv(const bf16* __restrict__ A,
                                                  const bf16* __restrict__ BT,
                                                  const float* __restrict__ bias,
                                                  bf16* __restrict__ qo,
                                                  bf16* __restrict__ ko,
                                                  bf16* __restrict__ vt,
                                                  const float2* __restrict__ tab) {
    int m0, n0;
    xcd_tile(TN / 128, (TN / 128) * (BL / 128), m0, n0);
    gemm_body<1>(A, BT, bias, nullptr, qo, ko, vt, tab, m0, n0, TN, Dm);
}
__global__ __launch_bounds__(256) void k_gemm_out(const bf16* __restrict__ A,
                                                  const bf16* __restrict__ BT,
                                                  const float* __restrict__ bias,
                                                  float* __restrict__ C) {
    int m0, n0;
    xcd_tile(Dm / 128, (Dm / 128) * (BL / 128), m0, n0);
    gemm_body<0>(A, BT, bias, C, nullptr, nullptr, nullptr, nullptr, m0, n0, Dm, Dm);
}

// ---------------- stage 3: flash attention (swapped-operand, 32x32x16) ------
// R10 = R6 structure (62.6us known-good) + permlane32_swap P-exchange ONLY.
// Scalar cross-half reductions stay on __shfl_xor (R9 post-mortem: swap of
// two identical-valued operands gets register-coalesced -> self-swap garbage).
DEV f32x16 mfma32(bf16x8 a, bf16x8 b, f32x16 c) {
    return __builtin_amdgcn_mfma_f32_32x32x16_bf16(a, b, c, 0, 0, 0);
}
DEV unsigned packbf(float lo, float hi) {
    unsigned short a = __builtin_bit_cast(unsigned short, (bf16)lo);
    unsigned short b = __builtin_bit_cast(unsigned short, (bf16)hi);
    return (unsigned)a | ((unsigned)b << 16);
}

DEV void stage_k(const char* kb, char* dst, int j0, int qw, int lane) {
#pragma unroll
    for (int c = 0; c < 2; ++c) {
        const int j = qw * 2 + c;              // chunk 0..7 (wave-uniform)
        const int rsw = lane ^ j;              // pre-swizzled source row
        __builtin_amdgcn_global_load_lds(AS1(kb + (size_t)(j0 + rsw) * 128 + j * 16),
                                         AS3(dst + j * 1024), 16, 0, 0);
    }
}
DEV void stage_v(const char* vb, char* dst, int j0, int qw, int lane) {
#pragma unroll
    for (int c = 0; c < 2; ++c) {
        const int j = qw * 2 + c;
        const int rsw = lane ^ j;
        __builtin_amdgcn_global_load_lds(AS1(vb + (size_t)rsw * 4096 + (size_t)j0 * 2 + j * 16),
                                         AS3(dst + j * 1024), 16, 0, 0);
    }
}

__global__ __launch_bounds__(512, 4) void k_attn(const bf16* __restrict__ Q,
                                                 const bf16* __restrict__ Kt,
                                                 const bf16* __restrict__ Vt,
                                                 bf16* __restrict__ Op) {
    __shared__ uint4 smem4[4096];   // 64KB: 2 halves x (2 bufs x [K 8K | V 8K])
    char* base = (char*)smem4;
    const int tid = threadIdx.x;
    const int w = tid >> 6, lane = tid & 63;
    const int qw = w & 3, s = w >> 2;
    const int hi = lane >> 5, l31 = lane & 31;
    const int bid = blockIdx.x;
    const int bh = bid >> 4, qt = bid & 15;
    const int q0 = qt * 128 + qw * 32;
    const char* qb = (const char*)(Q + (size_t)bh * Lseq * 64);
    const char* kb = (const char*)(Kt + (size_t)bh * Lseq * 64);
    const char* vb = (const char*)(Vt + (size_t)bh * 64 * Lseq);
    char* setb = base + s * 32768;             // this half's pipeline
    const int jbase = s * 16;                  // this half's first tile index

    // Q frags (B-operand): elem i = Q[q0+l31][kst*16 + hi*8 + i]
    bf16x8 qf[4];
#pragma unroll
    for (int kst = 0; kst < 4; ++kst)
        qf[kst] = *(const bf16x8*)(qb + (size_t)(q0 + l31) * 128 + kst * 32 + hi * 16);

    f32x16 o0 = {}, o1 = {};
    float m = -1e30f, lsum = 0.f;

    // prologue: stage tile 0 of this half into buf 0
    stage_k(kb, setb, jbase * 64, qw, lane);
    stage_v(vb, setb + 8192, jbase * 64, qw, lane);
    __syncthreads();

    for (int t = 0; t < 16; ++t) {
        const int cur = t & 1;
        const char* Kl = setb + cur * 16384;
        const char* Vl = Kl + 8192;
        char* Kn = setb + (cur ^ 1) * 16384;
        char* Vn = Kn + 8192;

        // async-stage next tile (drains at this iteration's end barrier)
        if (t < 15) {
            stage_k(kb, Kn, (jbase + t + 1) * 64, qw, lane);
            stage_v(vb, Vn, (jbase + t + 1) * 64, qw, lane);
        }

        // S^T = K * Q^T : s0 = j rows 0..31, s1 = 32..63 (col q = l31)
        f32x16 s0 = {}, s1 = {};
        __builtin_amdgcn_s_setprio(1);
#pragma unroll
        for (int kst = 0; kst < 4; ++kst) {
            const int jK = kst * 2 + hi;
            const int x = l31 ^ jK;            // jK<8: flips low 3 bits only
            bf16x8 ka = *(const bf16x8*)(Kl + jK * 1024 + x * 16);
            bf16x8 kc = *(const bf16x8*)(Kl + jK * 1024 + (32 + x) * 16);
            s0 = mfma32(ka, qf[kst], s0);
            s1 = mfma32(kc, qf[kst], s1);
        }
        __builtin_amdgcn_s_setprio(0);

        // lane-local online softmax (exp2 domain) for row q = l31
        float pm = fmaxf(s0[0], s0[1]);
#pragma unroll
        for (int r = 2; r < 16; ++r) pm = fmaxf(pm, s0[r]);
#pragma unroll
        for (int r = 0; r < 16; ++r) pm = fmaxf(pm, s1[r]);
        pm = fmaxf(pm, __shfl_xor(pm, 32));
        if (!__all(pm <= m + 8.0f)) {          // defer-max (T13), log2 units
            float mn = fmaxf(m, pm);
            float sc = exp2_fast(m - mn);
#pragma unroll
            for (int r = 0; r < 16; ++r) { o0[r] *= sc; o1[r] *= sc; }
            lsum *= sc; m = mn;
        }
        float rs = 0.f;
#pragma unroll
        for (int r = 0; r < 16; ++r) { s0[r] = exp2_fast(s0[r] - m); rs += s0[r]; }
#pragma unroll
        for (int r = 0; r < 16; ++r) { s1[r] = exp2_fast(s1[r] - m); rs += s1[r]; }
        rs += __shfl_xor(rs, 32);
        lsum += rs;

        // pack P to bf16 pairs; cross-half exchange = 8 in-place permlane
        // swaps on DISTINCT-valued register pairs (safe; see plswap note)
        unsigned u[16];
#pragma unroll
        for (int t2 = 0; t2 < 8; ++t2) {
            u[t2]     = packbf(s0[2 * t2], s0[2 * t2 + 1]);
            u[8 + t2] = packbf(s1[2 * t2], s1[2 * t2 + 1]);
        }
        bf16x8 pf[2][2];
#pragma unroll
        for (int J = 0; J < 2; ++J)
#pragma unroll
            for (int st = 0; st < 2; ++st) {
                const int t0 = J * 8 + st * 4;
                plswap(u[t0 + 0], u[t0 + 2]);
                plswap(u[t0 + 1], u[t0 + 3]);
                union { unsigned wd[4]; bf16x8 v; } f;
                f.wd[0] = u[t0 + 0];
                f.wd[1] = u[t0 + 1];
                f.wd[2] = u[t0 + 2];
                f.wd[3] = u[t0 + 3];
                pf[J][st] = f.v;
            }

        // O^T += V^T * P^T : o0 = d rows 0..31, o1 = 32..63 (col q = l31)
        __builtin_amdgcn_s_setprio(1);
#pragma unroll
        for (int J = 0; J < 2; ++J)
#pragma unroll
            for (int st = 0; st < 2; ++st) {
                const int jV = J * 4 + st * 2 + hi;
                const int x = l31 ^ jV;
                bf16x8 v0 = *(const bf16x8*)(Vl + jV * 1024 + x * 16);
                bf16x8 v1 = *(const bf16x8*)(Vl + jV * 1024 + (32 + x) * 16);
                o0 = mfma32(v0, pf[J][st], o0);
                o1 = mfma32(v1, pf[J][st], o1);
            }
        __builtin_amdgcn_s_setprio(0);
        __syncthreads();
    }

    // ---- combine the two KV halves (LDS exchange; K/V buffers now dead) ----
    float* ex = (float*)base;                   // per qw-wave region: 2176 floats
    if (s == 1) {
        float* r = ex + qw * 2176;
#pragma unroll
        for (int t = 0; t < 16; ++t) {
            r[t * 64 + lane] = o0[t];
            r[1024 + t * 64 + lane] = o1[t];
        }
        r[2048 + lane] = m;
        r[2112 + lane] = lsum;
    }
    __syncthreads();
    if (s == 0) {
        float* r = ex + qw * 2176;
        const float mb = r[2048 + lane], lb = r[2112 + lane];
        const float M = fmaxf(m, mb);
        const float wa = exp2_fast(m - M), wb = exp2_fast(mb - M);
        const float inv = 1.0f / (wa * lsum + wb * lb);
        const float fa = wa * inv, fb = wb * inv;
        const int b = bh >> 4, h = bh & 15;
        bf16* dst = Op + (size_t)(b * Lseq + q0 + l31) * Dm + h * 64;
        // epilogue layout: lane owns col q = l31; rows d = (r&3)+8*(r>>2)+4*hi
#pragma unroll
        for (int t = 0; t < 4; ++t) {
            bf16x4 p0, p1;
#pragma unroll
            for (int i = 0; i < 4; ++i) {
                p0[i] = (bf16)(o0[4 * t + i] * fa + r[(4 * t + i) * 64 + lane] * fb);
                p1[i] = (bf16)(o1[4 * t + i] * fa + r[1024 + (4 * t + i) * 64 + lane] * fb);
            }
            *(bf16x4*)(dst + 8 * t + 4 * hi) = p0;
            *(bf16x4*)(dst + 32 + 8 * t + 4 * hi) = p1;
        }
    }
}

// ---------------- launch ----------------
extern "C" void kernel_launch(void* const* d_in, const int* in_sizes, int n_in,
                              void* d_out, int out_size, void* d_ws, size_t ws_size,
                              hipStream_t stream) {
    (void)in_sizes; (void)n_in; (void)out_size; (void)ws_size;
    const float* x    = (const float*)d_in[0];
    const float* Wqkv = (const float*)d_in[1];
    const float* bqkv = (const float*)d_in[2];
    const float* Wout = (const float*)d_in[3];
    const float* bout = (const float*)d_in[4];
    float* out = (float*)d_out;
    char* ws = (char*)d_ws;

    bf16* xbf    = (bf16*)(ws + OFF_XATT);
    bf16* att    = (bf16*)(ws + OFF_XATT);   // aliases xbf (dead after gemm_qkv)
    bf16* wqkvT  = (bf16*)(ws + OFF_WQKVT);
    bf16* woutT  = (bf16*)(ws + OFF_WOUTT);
    float2* tab  = (float2*)(ws + OFF_TAB);
    bf16* qb     = (bf16*)(ws + OFF_Q);
    bf16* kb     = (bf16*)(ws + OFF_K);
    bf16* vt     = (bf16*)(ws + OFF_VT);

    hipLaunchKernelGGL(k_convert, dim3((BL * Dm) / 8 / 256), dim3(256), 0, stream, x, xbf);
    hipLaunchKernelGGL(k_transpose, dim3(TN / 32, Dm / 32), dim3(32, 8), 0, stream, Wqkv, wqkvT, Dm, TN);
    hipLaunchKernelGGL(k_transpose, dim3(Dm / 32, Dm / 32), dim3(32, 8), 0, stream, Wout, woutT, Dm, Dm);
    hipLaunchKernelGGL(k_sincos, dim3(Lseq * 32 / 256), dim3(256), 0, stream, tab);
    hipLaunchKernelGGL(k_gemm_qkv, dim3((TN / 128) * (BL / 128)), dim3(256), 0, stream,
                       xbf, wqkvT, bqkv, qb, kb, vt, tab);
    hipLaunchKernelGGL(k_attn, dim3(32 * 16), dim3(512), 0, stream, qb, kb, vt, att);
    hipLaunchKernelGGL(k_gemm_out, dim3((Dm / 128) * (BL / 128)), dim3(256), 0, stream,
                       att, woutT, bout, out);
}